// Round 1
// baseline (3689.344 us; speedup 1.0000x reference)
//
#include <hip/hip_runtime.h>
#include <cfloat>
#include <cstddef>

#define B_SZ 16384
#define DIN  784
#define H_SZ 400
#define D_SZ 512
#define K_SZ 8192

// ---------------------------------------------------------------------------
// emb squared norms (one wave per codebook row) + zero the loss accumulators
// ---------------------------------------------------------------------------
__global__ __launch_bounds__(256)
void embsq_kernel(const float* __restrict__ emb, float* __restrict__ emb_sq,
                  float* __restrict__ accum) {
  if (blockIdx.x == 0 && threadIdx.x == 0) { accum[0] = 0.f; accum[1] = 0.f; }
  int row  = blockIdx.x * 4 + (threadIdx.x >> 6);
  int lane = threadIdx.x & 63;
  const float4* p = reinterpret_cast<const float4*>(emb + (size_t)row * D_SZ);
  float s = 0.f;
#pragma unroll
  for (int q = 0; q < 2; ++q) {
    float4 v = p[lane * 2 + q];
    s += v.x * v.x + v.y * v.y + v.z * v.z + v.w * v.w;
  }
#pragma unroll
  for (int off = 32; off > 0; off >>= 1) s += __shfl_down(s, off);
  if (lane == 0) emb_sq[row] = s;
}

// ---------------------------------------------------------------------------
// Generic fp32 GEMM: C = act(A @ Bw + bias).  64x64 tile, BK=16, 256 threads,
// 4x4 register micro-tile.  ACT: 0=none 1=relu 2=sigmoid.
// GATHER: A row r is emb[gidx[r]] (for the decoder's z_q input).
// BCE: fuse binary-cross-entropy partial sum against xb into the epilogue.
// M multiple of 64, Kd multiple of 16, N multiple of 4 (all true here).
// ---------------------------------------------------------------------------
template <int ACT, bool GATHER, bool BCE>
__global__ __launch_bounds__(256)
void gemm_kernel(const float* __restrict__ A, const float* __restrict__ Bw,
                 const float* __restrict__ bias, float* __restrict__ C,
                 int M, int N, int Kd,
                 const int* __restrict__ gidx,
                 const float* __restrict__ xb, float* __restrict__ loss_accum) {
  __shared__ float As[16][64];
  __shared__ float Bs[16][64];
  __shared__ float rsum[256];

  const int tid = threadIdx.x;
  const int tm = tid >> 4, tn = tid & 15;
  const int rowBase = blockIdx.y * 64;
  const int colBase = blockIdx.x * 64;

  // A staging: thread -> (m = tid>>2, 4 consecutive k at (tid&3)*4)
  const int lm = tid >> 2, ld0 = (tid & 3) * 4;
  const float* Arow;
  {
    const int grow = rowBase + lm;
    const long arow = GATHER ? (long)gidx[grow] : (long)grow;
    Arow = A + (size_t)arow * Kd;
  }
  // B staging: thread -> (k = tid>>4, 4 consecutive n at (tid&15)*4)
  const int bk = tid >> 4;
  const int bn = (tid & 15) * 4;
  const int bc = colBase + bn;

  float acc[4][4] = {};
  const int nk = Kd >> 4;
  for (int kt = 0; kt < nk; ++kt) {
    const int kd = kt << 4;
    float4 av = *reinterpret_cast<const float4*>(Arow + kd + ld0);
    float4 bv = make_float4(0.f, 0.f, 0.f, 0.f);
    if (bc < N) bv = *reinterpret_cast<const float4*>(Bw + (size_t)(kd + bk) * N + bc);
    __syncthreads();
    As[ld0 + 0][lm] = av.x; As[ld0 + 1][lm] = av.y;
    As[ld0 + 2][lm] = av.z; As[ld0 + 3][lm] = av.w;
    *reinterpret_cast<float4*>(&Bs[bk][bn]) = bv;
    __syncthreads();
#pragma unroll
    for (int kk = 0; kk < 16; ++kk) {
      float4 a = *reinterpret_cast<const float4*>(&As[kk][tm * 4]);
      float4 b = *reinterpret_cast<const float4*>(&Bs[kk][tn * 4]);
      const float ar[4] = {a.x, a.y, a.z, a.w};
      const float br[4] = {b.x, b.y, b.z, b.w};
#pragma unroll
      for (int i = 0; i < 4; ++i)
#pragma unroll
        for (int j = 0; j < 4; ++j) acc[i][j] += ar[i] * br[j];
    }
  }

  // epilogue
  float bce = 0.f;
  const int c0 = colBase + tn * 4;
  if (c0 < N) {  // N%4==0 -> all 4 cols in-bounds
    float4 b4 = *reinterpret_cast<const float4*>(bias + c0);
    const float bb[4] = {b4.x, b4.y, b4.z, b4.w};
#pragma unroll
    for (int i = 0; i < 4; ++i) {
      const int r = rowBase + tm * 4 + i;
      float o[4];
#pragma unroll
      for (int j = 0; j < 4; ++j) {
        float v = acc[i][j] + bb[j];
        if (ACT == 1) v = fmaxf(v, 0.f);
        if (ACT == 2) v = 1.f / (1.f + expf(-v));
        o[j] = v;
        if (BCE) {
          const float p  = fminf(fmaxf(v, 1e-7f), 1.f - 1e-7f);
          const float xv = xb[(size_t)r * N + c0 + j];
          bce += xv * logf(p) + (1.f - xv) * log1pf(-p);
        }
      }
      *reinterpret_cast<float4*>(C + (size_t)r * N + c0) =
          *reinterpret_cast<const float4*>(o);
    }
  }

  if (BCE) {
    rsum[tid] = bce;
    __syncthreads();
#pragma unroll
    for (int s = 128; s > 0; s >>= 1) {
      if (tid < s) rsum[tid] += rsum[tid + s];
      __syncthreads();
    }
    if (tid == 0) atomicAdd(loss_accum, rsum[0]);
  }
}

// ---------------------------------------------------------------------------
// Fused VQ: for 64 rows of z_e, scan all 8192 codebook entries computing
// score = ||e||^2 - 2*z.e (the ||z||^2 term is row-constant, argmin-invariant)
// via a 64x64 tiled fp32 GEMM; keep running (min,idx) in registers; reduce
// across the 16 column-threads per row at the end.  First-occurrence
// tie-breaking matches jnp.argmin (strict < within a thread's ascending cols,
// min-index on exact equality across threads).
// ---------------------------------------------------------------------------
__global__ __launch_bounds__(256)
void vq_kernel(const float* __restrict__ z_e, const float* __restrict__ emb,
               const float* __restrict__ emb_sq, int* __restrict__ idx_out) {
  __shared__ float As[16][64];
  __shared__ float Es[16][64];
  __shared__ float red_v[64][16];
  __shared__ int   red_i[64][16];

  const int tid = threadIdx.x;
  const int tm = tid >> 4, tn = tid & 15;
  const int rowBase = blockIdx.x * 64;
  const int lm = tid >> 2, ld0 = (tid & 3) * 4;
  const float* Arow = z_e + (size_t)(rowBase + lm) * D_SZ;

  float minv[4];
  int   mini[4];
#pragma unroll
  for (int i = 0; i < 4; ++i) { minv[i] = FLT_MAX; mini[i] = 0; }

  for (int ct = 0; ct < K_SZ / 64; ++ct) {
    const int colBase = ct * 64;
    const float* Erow = emb + (size_t)(colBase + lm) * D_SZ;
    float acc[4][4] = {};
    for (int kt = 0; kt < D_SZ / 16; ++kt) {
      const int kd = kt << 4;
      float4 av = *reinterpret_cast<const float4*>(Arow + kd + ld0);
      float4 ev = *reinterpret_cast<const float4*>(Erow + kd + ld0);
      __syncthreads();
      As[ld0 + 0][lm] = av.x; As[ld0 + 1][lm] = av.y;
      As[ld0 + 2][lm] = av.z; As[ld0 + 3][lm] = av.w;
      Es[ld0 + 0][lm] = ev.x; Es[ld0 + 1][lm] = ev.y;
      Es[ld0 + 2][lm] = ev.z; Es[ld0 + 3][lm] = ev.w;
      __syncthreads();
#pragma unroll
      for (int kk = 0; kk < 16; ++kk) {
        float4 a = *reinterpret_cast<const float4*>(&As[kk][tm * 4]);
        float4 e = *reinterpret_cast<const float4*>(&Es[kk][tn * 4]);
        const float ar[4] = {a.x, a.y, a.z, a.w};
        const float er[4] = {e.x, e.y, e.z, e.w};
#pragma unroll
        for (int i = 0; i < 4; ++i)
#pragma unroll
          for (int j = 0; j < 4; ++j) acc[i][j] += ar[i] * er[j];
      }
    }
#pragma unroll
    for (int j = 0; j < 4; ++j) {
      const int c = colBase + tn * 4 + j;
      const float sq = emb_sq[c];
#pragma unroll
      for (int i = 0; i < 4; ++i) {
        const float s = sq - 2.f * acc[i][j];
        if (s < minv[i]) { minv[i] = s; mini[i] = c; }
      }
    }
  }

#pragma unroll
  for (int i = 0; i < 4; ++i) {
    red_v[tm * 4 + i][tn] = minv[i];
    red_i[tm * 4 + i][tn] = mini[i];
  }
  __syncthreads();
  if (tid < 64) {
    float bv = red_v[tid][0];
    int   bi = red_i[tid][0];
#pragma unroll
    for (int t = 1; t < 16; ++t) {
      const float v = red_v[tid][t];
      const int  ii = red_i[tid][t];
      if (v < bv || (v == bv && ii < bi)) { bv = v; bi = ii; }
    }
    idx_out[rowBase + tid] = bi;
  }
}

// ---------------------------------------------------------------------------
// sum((z_e - emb[idx])^2)  ->  accum[1]   (embed_loss == commit_loss forward)
// ---------------------------------------------------------------------------
__global__ __launch_bounds__(256)
void vqloss_kernel(const float* __restrict__ z_e, const float* __restrict__ emb,
                   const int* __restrict__ idx, float* __restrict__ accum) {
  __shared__ float rsum[256];
  const int tid = threadIdx.x;
  const size_t stride = (size_t)gridDim.x * blockDim.x;
  const size_t total = (size_t)B_SZ * (D_SZ / 4);
  float s = 0.f;
  for (size_t e = (size_t)blockIdx.x * blockDim.x + tid; e < total; e += stride) {
    const size_t b = e >> 7;              // 128 float4 per row
    const int   d4 = (int)(e & 127);
    float4 z = reinterpret_cast<const float4*>(z_e)[e];
    float4 q = reinterpret_cast<const float4*>(emb + (size_t)idx[b] * D_SZ)[d4];
    const float dx = z.x - q.x, dy = z.y - q.y, dz = z.z - q.z, dw = z.w - q.w;
    s += dx * dx + dy * dy + dz * dz + dw * dw;
  }
  rsum[tid] = s;
  __syncthreads();
#pragma unroll
  for (int st = 128; st > 0; st >>= 1) {
    if (tid < st) rsum[tid] += rsum[tid + st];
    __syncthreads();
  }
  if (tid == 0) atomicAdd(accum + 1, rsum[0]);
}

// ---------------------------------------------------------------------------
__global__ void finalize_kernel(const float* __restrict__ accum,
                                float* __restrict__ out) {
  const float rl = -accum[0] / ((float)B_SZ * (float)DIN);
  const float el = accum[1] / (float)B_SZ;
  out[(size_t)B_SZ * DIN + 0] = rl;
  out[(size_t)B_SZ * DIN + 1] = el;
  out[(size_t)B_SZ * DIN + 2] = el;
}

// ---------------------------------------------------------------------------
extern "C" void kernel_launch(void* const* d_in, const int* in_sizes, int n_in,
                              void* d_out, int out_size, void* d_ws,
                              size_t ws_size, hipStream_t stream) {
  const float* x   = (const float*)d_in[0];
  const float* W1  = (const float*)d_in[1];
  const float* b1  = (const float*)d_in[2];
  const float* W2  = (const float*)d_in[3];
  const float* b2  = (const float*)d_in[4];
  const float* W3  = (const float*)d_in[5];
  const float* b3  = (const float*)d_in[6];
  const float* W4  = (const float*)d_in[7];
  const float* b4  = (const float*)d_in[8];
  const float* emb = (const float*)d_in[9];
  float* out = (float*)d_out;

  // workspace layout (floats):
  float* ws    = (float*)d_ws;
  float* h     = ws;                               // 16384*400 (h1, later h3)
  float* z_e   = h + (size_t)B_SZ * H_SZ;          // 16384*512
  float* esq   = z_e + (size_t)B_SZ * D_SZ;        // 8192
  float* accum = esq + K_SZ;                       // [0]=bce sum, [1]=vq sum
  int*   idx   = (int*)(accum + 8);                // 16384 ints

  // 1) codebook norms + zero accumulators
  embsq_kernel<<<K_SZ / 4, 256, 0, stream>>>(emb, esq, accum);
  // 2) h1 = relu(x @ W1 + b1)
  gemm_kernel<1, false, false><<<dim3((H_SZ + 63) / 64, B_SZ / 64), 256, 0, stream>>>(
      x, W1, b1, h, B_SZ, H_SZ, DIN, nullptr, nullptr, nullptr);
  // 3) z_e = h1 @ W2 + b2
  gemm_kernel<0, false, false><<<dim3((D_SZ + 63) / 64, B_SZ / 64), 256, 0, stream>>>(
      h, W2, b2, z_e, B_SZ, D_SZ, H_SZ, nullptr, nullptr, nullptr);
  // 4) idx = argmin_k ||z_e - emb_k||^2
  vq_kernel<<<B_SZ / 64, 256, 0, stream>>>(z_e, emb, esq, idx);
  // 5) embed/commit loss sum
  vqloss_kernel<<<1024, 256, 0, stream>>>(z_e, emb, idx, accum);
  // 6) h3 = relu(emb[idx] @ W3 + b3)   (z_q gathered on the fly)
  gemm_kernel<1, true, false><<<dim3((H_SZ + 63) / 64, B_SZ / 64), 256, 0, stream>>>(
      emb, W3, b3, h, B_SZ, H_SZ, D_SZ, idx, nullptr, nullptr);
  // 7) x_reconst = sigmoid(h3 @ W4 + b4), fused BCE partial sums
  gemm_kernel<2, false, true><<<dim3((DIN + 63) / 64, B_SZ / 64), 256, 0, stream>>>(
      h, W4, b4, out, B_SZ, DIN, H_SZ, nullptr, x, accum);
  // 8) scalars
  finalize_kernel<<<1, 1, 0, stream>>>(accum, out);
}

// Round 2
// 700.631 us; speedup vs baseline: 5.2657x; 5.2657x over previous
//
#include <hip/hip_runtime.h>
#include <cfloat>
#include <cstddef>

#define B_SZ 16384
#define DIN  784
#define H_SZ 400
#define D_SZ 512
#define K_SZ 8192

typedef short bf16x8 __attribute__((ext_vector_type(8)));
typedef float f32x4  __attribute__((ext_vector_type(4)));

__device__ __forceinline__ unsigned short f2bf(float f) {
  unsigned u = __float_as_uint(f);
  unsigned r = (u + 0x7FFFu + ((u >> 16) & 1u)) >> 16;
  return (unsigned short)r;
}

// ---------------------------------------------------------------------------
// emb squared norms (one wave per codebook row) + zero the loss accumulators
// ---------------------------------------------------------------------------
__global__ __launch_bounds__(256)
void embsq_kernel(const float* __restrict__ emb, float* __restrict__ emb_sq,
                  float* __restrict__ accum) {
  if (blockIdx.x == 0 && threadIdx.x == 0) { accum[0] = 0.f; accum[1] = 0.f; }
  int row  = blockIdx.x * 4 + (threadIdx.x >> 6);
  int lane = threadIdx.x & 63;
  const float4* p = reinterpret_cast<const float4*>(emb + (size_t)row * D_SZ);
  float s = 0.f;
#pragma unroll
  for (int q = 0; q < 2; ++q) {
    float4 v = p[lane * 2 + q];
    s += v.x * v.x + v.y * v.y + v.z * v.z + v.w * v.w;
  }
#pragma unroll
  for (int off = 32; off > 0; off >>= 1) s += __shfl_down(s, off);
  if (lane == 0) emb_sq[row] = s;
}

// ---------------------------------------------------------------------------
// fp32 -> bf16 cast, vectorized, grid-stride
// ---------------------------------------------------------------------------
__global__ __launch_bounds__(256)
void cast_bf16_kernel(const float* __restrict__ src,
                      unsigned short* __restrict__ dst, int n4) {
  int i = blockIdx.x * 256 + threadIdx.x;
  const int stride = gridDim.x * 256;
  for (; i < n4; i += stride) {
    float4 v = reinterpret_cast<const float4*>(src)[i];
    ushort4 u;
    u.x = f2bf(v.x); u.y = f2bf(v.y); u.z = f2bf(v.z); u.w = f2bf(v.w);
    reinterpret_cast<ushort4*>(dst)[i] = u;
  }
}

// ---------------------------------------------------------------------------
// Generic fp32 GEMM: C = act(A @ Bw + bias).  64x64 tile, BK=16, 256 threads,
// 4x4 register micro-tile.  ACT: 0=none 1=relu 2=sigmoid.
// ---------------------------------------------------------------------------
template <int ACT, bool GATHER, bool BCE>
__global__ __launch_bounds__(256)
void gemm_kernel(const float* __restrict__ A, const float* __restrict__ Bw,
                 const float* __restrict__ bias, float* __restrict__ C,
                 int M, int N, int Kd,
                 const int* __restrict__ gidx,
                 const float* __restrict__ xb, float* __restrict__ loss_accum) {
  __shared__ float As[16][64];
  __shared__ float Bs[16][64];
  __shared__ float rsum[256];

  const int tid = threadIdx.x;
  const int tm = tid >> 4, tn = tid & 15;
  const int rowBase = blockIdx.y * 64;
  const int colBase = blockIdx.x * 64;

  const int lm = tid >> 2, ld0 = (tid & 3) * 4;
  const float* Arow;
  {
    const int grow = rowBase + lm;
    const long arow = GATHER ? (long)gidx[grow] : (long)grow;
    Arow = A + (size_t)arow * Kd;
  }
  const int bk = tid >> 4;
  const int bn = (tid & 15) * 4;
  const int bc = colBase + bn;

  float acc[4][4] = {};
  const int nk = Kd >> 4;
  for (int kt = 0; kt < nk; ++kt) {
    const int kd = kt << 4;
    float4 av = *reinterpret_cast<const float4*>(Arow + kd + ld0);
    float4 bv = make_float4(0.f, 0.f, 0.f, 0.f);
    if (bc < N) bv = *reinterpret_cast<const float4*>(Bw + (size_t)(kd + bk) * N + bc);
    __syncthreads();
    As[ld0 + 0][lm] = av.x; As[ld0 + 1][lm] = av.y;
    As[ld0 + 2][lm] = av.z; As[ld0 + 3][lm] = av.w;
    *reinterpret_cast<float4*>(&Bs[bk][bn]) = bv;
    __syncthreads();
#pragma unroll
    for (int kk = 0; kk < 16; ++kk) {
      float4 a = *reinterpret_cast<const float4*>(&As[kk][tm * 4]);
      float4 b = *reinterpret_cast<const float4*>(&Bs[kk][tn * 4]);
      const float ar[4] = {a.x, a.y, a.z, a.w};
      const float br[4] = {b.x, b.y, b.z, b.w};
#pragma unroll
      for (int i = 0; i < 4; ++i)
#pragma unroll
        for (int j = 0; j < 4; ++j) acc[i][j] += ar[i] * br[j];
    }
  }

  float bce = 0.f;
  const int c0 = colBase + tn * 4;
  if (c0 < N) {
    float4 b4 = *reinterpret_cast<const float4*>(bias + c0);
    const float bb[4] = {b4.x, b4.y, b4.z, b4.w};
#pragma unroll
    for (int i = 0; i < 4; ++i) {
      const int r = rowBase + tm * 4 + i;
      float o[4];
#pragma unroll
      for (int j = 0; j < 4; ++j) {
        float v = acc[i][j] + bb[j];
        if (ACT == 1) v = fmaxf(v, 0.f);
        if (ACT == 2) v = 1.f / (1.f + expf(-v));
        o[j] = v;
        if (BCE) {
          const float p  = fminf(fmaxf(v, 1e-7f), 1.f - 1e-7f);
          const float xv = xb[(size_t)r * N + c0 + j];
          bce += xv * logf(p) + (1.f - xv) * log1pf(-p);
        }
      }
      *reinterpret_cast<float4*>(C + (size_t)r * N + c0) =
          *reinterpret_cast<const float4*>(o);
    }
  }

  if (BCE) {
    rsum[tid] = bce;
    __syncthreads();
#pragma unroll
    for (int s = 128; s > 0; s >>= 1) {
      if (tid < s) rsum[tid] += rsum[tid + s];
      __syncthreads();
    }
    if (tid == 0) atomicAdd(loss_accum, rsum[0]);
  }
}

// ---------------------------------------------------------------------------
// MFMA VQ argmin.  Block = 512 thr (8 waves); wave holds 32 z_e rows in regs
// (full K=512 of bf16 A-fragments).  Grid = 64 row-blocks x 4 code-chunks
// (2048 codes each), block-id arranged so a chunk's 2MB of emb pins to one
// XCD pair's L2.  emb tile (32 codes x 512) double-buffered in LDS via
// global_load_lds(16B) with XOR swizzle: LDS[row][u] = G[row][u ^ (row&7)]
// (inverse-swizzled per-lane global source, linear LDS dest, swizzled read).
// score = ||e||^2 - 2*z.e  (row-constant ||z||^2 dropped: argmin-invariant).
// ---------------------------------------------------------------------------
__global__ __launch_bounds__(512, 2)
void vq_mfma_kernel(const unsigned short* __restrict__ zeb,
                    const unsigned short* __restrict__ embb,
                    const float* __restrict__ emb_sq,
                    float* __restrict__ cand_val, int* __restrict__ cand_idx) {
  __shared__ unsigned short etile[2][32 * 512];

  const int tid  = threadIdx.x;
  const int w    = tid >> 6;    // wave 0..7
  const int lane = tid & 63;
  const int cq   = lane >> 4;   // 0..3
  const int cr   = lane & 15;   // 0..15

  const int bid      = blockIdx.x;
  const int chunk    = (bid >> 1) & 3;                // XCD-pair per chunk
  const int rowblock = ((bid >> 3) << 1) | (bid & 1); // 0..63
  const int rowBase  = rowblock * 256;
  const int codeBase = chunk * 2048;

  // ---- A fragments: 32 rows/wave, K=512, register-resident ----
  bf16x8 a[2][16];
  {
    const unsigned short* z0 =
        zeb + (size_t)(rowBase + w * 32 + cr) * D_SZ + cq * 8;
#pragma unroll
    for (int ks = 0; ks < 16; ++ks) {
      a[0][ks] = *reinterpret_cast<const bf16x8*>(z0 + ks * 32);
      a[1][ks] = *reinterpret_cast<const bf16x8*>(z0 + 16 * D_SZ + ks * 32);
    }
  }

  float minv[2][4];
  int   mini[2][4];
#pragma unroll
  for (int mf = 0; mf < 2; ++mf)
#pragma unroll
    for (int r4 = 0; r4 < 4; ++r4) { minv[mf][r4] = FLT_MAX; mini[mf][r4] = 0; }

  auto stage = [&](int tt, int bb) {
#pragma unroll
    for (int r = 0; r < 4; ++r) {
      const int row = r * 8 + w;  // row&7 == w
      const unsigned short* g =
          embb + (size_t)(codeBase + tt * 32 + row) * D_SZ + ((lane ^ w) << 3);
      __builtin_amdgcn_global_load_lds(
          (const __attribute__((address_space(1))) unsigned int*)g,
          (__attribute__((address_space(3))) unsigned int*)&etile[bb][row * D_SZ],
          16, 0, 0);
    }
  };

  stage(0, 0);
  __syncthreads();  // compiler drains vmcnt before s_barrier

  const char* lds0 = (const char*)etile[0];
  const char* lds1 = (const char*)etile[1];
  const int sw  = (cr & 7) << 4;       // read-side XOR (row&7 == cr&7 for both nf)
  const int rbA = cr * 1024;           // nf=0 row bytes
  const int rbB = (16 + cr) * 1024;    // nf=1 row bytes

#pragma unroll 2
  for (int t = 0; t < 64; ++t) {
    const int bb = t & 1;
    if (t + 1 < 64) stage(t + 1, bb ^ 1);
    const char* buf = bb ? lds1 : lds0;

    f32x4 acc[2][2] = {};
#pragma unroll
    for (int ks = 0; ks < 16; ++ks) {
      const int off = (ks * 64 + cq * 16) ^ sw;
      bf16x8 b0 = *reinterpret_cast<const bf16x8*>(buf + rbA + off);
      bf16x8 b1 = *reinterpret_cast<const bf16x8*>(buf + rbB + off);
      acc[0][0] = __builtin_amdgcn_mfma_f32_16x16x32_bf16(a[0][ks], b0, acc[0][0], 0, 0, 0);
      acc[1][0] = __builtin_amdgcn_mfma_f32_16x16x32_bf16(a[1][ks], b0, acc[1][0], 0, 0, 0);
      acc[0][1] = __builtin_amdgcn_mfma_f32_16x16x32_bf16(a[0][ks], b1, acc[0][1], 0, 0, 0);
      acc[1][1] = __builtin_amdgcn_mfma_f32_16x16x32_bf16(a[1][ks], b1, acc[1][1], 0, 0, 0);
    }

    const int tb = codeBase + t * 32;
#pragma unroll
    for (int nf = 0; nf < 2; ++nf) {
      const int c = tb + nf * 16 + cr;
      const float sq = emb_sq[c];
#pragma unroll
      for (int mf = 0; mf < 2; ++mf)
#pragma unroll
        for (int r4 = 0; r4 < 4; ++r4) {
          const float s = sq - 2.f * acc[mf][nf][r4];
          if (s < minv[mf][r4]) { minv[mf][r4] = s; mini[mf][r4] = c; }
        }
    }
    __syncthreads();
  }

  // cross-lane argmin over the 16 column-lanes (same cq group), tie -> min idx
#pragma unroll
  for (int mf = 0; mf < 2; ++mf)
#pragma unroll
    for (int r4 = 0; r4 < 4; ++r4) {
      float v = minv[mf][r4];
      int   i = mini[mf][r4];
#pragma unroll
      for (int m = 1; m < 16; m <<= 1) {
        float ov = __shfl_xor(v, m, 64);
        int   oi = __shfl_xor(i, m, 64);
        if (ov < v || (ov == v && oi < i)) { v = ov; i = oi; }
      }
      if (cr == 0) {
        const int row = rowBase + w * 32 + mf * 16 + cq * 4 + r4;
        cand_val[(size_t)chunk * B_SZ + row] = v;
        cand_idx[(size_t)chunk * B_SZ + row] = i;
      }
    }
}

// ---------------------------------------------------------------------------
__global__ __launch_bounds__(256)
void vq_finalize_kernel(const float* __restrict__ cv, const int* __restrict__ ci,
                        int* __restrict__ idx) {
  const int r = blockIdx.x * 256 + threadIdx.x;
  float bv = cv[r];
  int   bi = ci[r];
#pragma unroll
  for (int c = 1; c < 4; ++c) {
    const float v = cv[(size_t)c * B_SZ + r];
    const int  i2 = ci[(size_t)c * B_SZ + r];
    if (v < bv || (v == bv && i2 < bi)) { bv = v; bi = i2; }
  }
  idx[r] = bi;
}

// ---------------------------------------------------------------------------
// sum((z_e - emb[idx])^2) -> accum[1]
// ---------------------------------------------------------------------------
__global__ __launch_bounds__(256)
void vqloss_kernel(const float* __restrict__ z_e, const float* __restrict__ emb,
                   const int* __restrict__ idx, float* __restrict__ accum) {
  __shared__ float rsum[256];
  const int tid = threadIdx.x;
  const size_t stride = (size_t)gridDim.x * blockDim.x;
  const size_t total = (size_t)B_SZ * (D_SZ / 4);
  float s = 0.f;
  for (size_t e = (size_t)blockIdx.x * blockDim.x + tid; e < total; e += stride) {
    const size_t b = e >> 7;
    const int   d4 = (int)(e & 127);
    float4 z = reinterpret_cast<const float4*>(z_e)[e];
    float4 q = reinterpret_cast<const float4*>(emb + (size_t)idx[b] * D_SZ)[d4];
    const float dx = z.x - q.x, dy = z.y - q.y, dz = z.z - q.z, dw = z.w - q.w;
    s += dx * dx + dy * dy + dz * dz + dw * dw;
  }
  rsum[tid] = s;
  __syncthreads();
#pragma unroll
  for (int st = 128; st > 0; st >>= 1) {
    if (tid < st) rsum[tid] += rsum[tid + st];
    __syncthreads();
  }
  if (tid == 0) atomicAdd(accum + 1, rsum[0]);
}

// ---------------------------------------------------------------------------
__global__ void finalize_kernel(const float* __restrict__ accum,
                                float* __restrict__ out) {
  const float rl = -accum[0] / ((float)B_SZ * (float)DIN);
  const float el = accum[1] / (float)B_SZ;
  out[(size_t)B_SZ * DIN + 0] = rl;
  out[(size_t)B_SZ * DIN + 1] = el;
  out[(size_t)B_SZ * DIN + 2] = el;
}

// ---------------------------------------------------------------------------
extern "C" void kernel_launch(void* const* d_in, const int* in_sizes, int n_in,
                              void* d_out, int out_size, void* d_ws,
                              size_t ws_size, hipStream_t stream) {
  const float* x   = (const float*)d_in[0];
  const float* W1  = (const float*)d_in[1];
  const float* b1  = (const float*)d_in[2];
  const float* W2  = (const float*)d_in[3];
  const float* b2  = (const float*)d_in[4];
  const float* W3  = (const float*)d_in[5];
  const float* b3  = (const float*)d_in[6];
  const float* W4  = (const float*)d_in[7];
  const float* b4  = (const float*)d_in[8];
  const float* emb = (const float*)d_in[9];
  float* out = (float*)d_out;

  // workspace layout (float slots):
  float* ws    = (float*)d_ws;
  float* h     = ws;                               // 16384*400 = 6553600
  float* z_e   = h + (size_t)B_SZ * H_SZ;          // 16384*512
  float* esq   = z_e + (size_t)B_SZ * D_SZ;        // 8192
  float* accum = esq + K_SZ;                       // [0]=bce, [1]=vq
  int*   idx   = (int*)(accum + 8);                // 16384 ints

  // VQ-phase sub-layout inside h (h1 is dead between gemm2 and gemm3):
  unsigned short* zeb  = (unsigned short*)h;                 // 16384*512 bf16
  unsigned short* embb = (unsigned short*)(h + 4194304);     // 8192*512 bf16
  float* cand_val = h + 4194304 + 2097152;                   // 4*16384 f32
  int*   cand_idx = (int*)(h + 4194304 + 2097152 + 65536);   // 4*16384 i32

  // 1) codebook norms + zero accumulators
  embsq_kernel<<<K_SZ / 4, 256, 0, stream>>>(emb, esq, accum);
  // 2) h1 = relu(x @ W1 + b1)
  gemm_kernel<1, false, false><<<dim3((H_SZ + 63) / 64, B_SZ / 64), 256, 0, stream>>>(
      x, W1, b1, h, B_SZ, H_SZ, DIN, nullptr, nullptr, nullptr);
  // 3) z_e = h1 @ W2 + b2
  gemm_kernel<0, false, false><<<dim3((D_SZ + 63) / 64, B_SZ / 64), 256, 0, stream>>>(
      h, W2, b2, z_e, B_SZ, D_SZ, H_SZ, nullptr, nullptr, nullptr);
  // 4) bf16 casts (h1 dead now; zeb/embb live inside h region)
  cast_bf16_kernel<<<1024, 256, 0, stream>>>(z_e, zeb, (B_SZ * D_SZ) / 4);
  cast_bf16_kernel<<<512, 256, 0, stream>>>(emb, embb, (K_SZ * D_SZ) / 4);
  // 5) MFMA VQ argmin (per-chunk candidates)
  vq_mfma_kernel<<<256, 512, 0, stream>>>(zeb, embb, esq, cand_val, cand_idx);
  // 6) reduce 4 chunk candidates per row
  vq_finalize_kernel<<<B_SZ / 256, 256, 0, stream>>>(cand_val, cand_idx, idx);
  // 7) embed/commit loss sum
  vqloss_kernel<<<1024, 256, 0, stream>>>(z_e, emb, idx, accum);
  // 8) h3 = relu(emb[idx] @ W3 + b3)
  gemm_kernel<1, true, false><<<dim3((H_SZ + 63) / 64, B_SZ / 64), 256, 0, stream>>>(
      emb, W3, b3, h, B_SZ, H_SZ, D_SZ, idx, nullptr, nullptr);
  // 9) x_reconst = sigmoid(h3 @ W4 + b4), fused BCE
  gemm_kernel<2, false, true><<<dim3((DIN + 63) / 64, B_SZ / 64), 256, 0, stream>>>(
      h, W4, b4, out, B_SZ, DIN, H_SZ, nullptr, x, accum);
  // 10) scalars
  finalize_kernel<<<1, 1, 0, stream>>>(accum, out);
}

// Round 3
// 319.727 us; speedup vs baseline: 11.5390x; 2.1913x over previous
//
#include <hip/hip_runtime.h>
#include <cfloat>
#include <cstddef>

#define B_SZ 16384
#define DIN  784
#define H_SZ 400
#define D_SZ 512
#define K_SZ 8192

#define DIN_P 800   // 784 padded to 25*32
#define H_P   416   // 400 padded to 13*32

typedef short bf16x8 __attribute__((ext_vector_type(8)));
typedef float f32x4  __attribute__((ext_vector_type(4)));

__device__ __forceinline__ unsigned short f2bf(float f) {
  unsigned u = __float_as_uint(f);
  unsigned r = (u + 0x7FFFu + ((u >> 16) & 1u)) >> 16;
  return (unsigned short)r;
}
__device__ __forceinline__ float bf2f(unsigned short h) {
  return __uint_as_float(((unsigned)h) << 16);
}

// ---------------------------------------------------------------------------
// emb squared norms + zero the loss accumulators
// ---------------------------------------------------------------------------
__global__ __launch_bounds__(256)
void embsq_kernel(const float* __restrict__ emb, float* __restrict__ emb_sq,
                  float* __restrict__ accum) {
  if (blockIdx.x == 0 && threadIdx.x == 0) { accum[0] = 0.f; accum[1] = 0.f; }
  int row  = blockIdx.x * 4 + (threadIdx.x >> 6);
  int lane = threadIdx.x & 63;
  const float4* p = reinterpret_cast<const float4*>(emb + (size_t)row * D_SZ);
  float s = 0.f;
#pragma unroll
  for (int q = 0; q < 2; ++q) {
    float4 v = p[lane * 2 + q];
    s += v.x * v.x + v.y * v.y + v.z * v.z + v.w * v.w;
  }
#pragma unroll
  for (int off = 32; off > 0; off >>= 1) s += __shfl_down(s, off);
  if (lane == 0) emb_sq[row] = s;
}

// ---------------------------------------------------------------------------
// fp32 -> bf16 cast (contiguous), grid-stride
// ---------------------------------------------------------------------------
__global__ __launch_bounds__(256)
void cast_bf16_kernel(const float* __restrict__ src,
                      unsigned short* __restrict__ dst, int n4) {
  int i = blockIdx.x * 256 + threadIdx.x;
  const int stride = gridDim.x * 256;
  for (; i < n4; i += stride) {
    float4 v = reinterpret_cast<const float4*>(src)[i];
    ushort4 u;
    u.x = f2bf(v.x); u.y = f2bf(v.y); u.z = f2bf(v.z); u.w = f2bf(v.w);
    reinterpret_cast<ushort4*>(dst)[i] = u;
  }
}

// ---------------------------------------------------------------------------
// x [16384][784] fp32 -> xb [16384][800] bf16, zero-padded cols 784..799
// 784 = 196*4, so ushort4 units 0..195 are data, 196..199 are pad.
// ---------------------------------------------------------------------------
__global__ __launch_bounds__(256)
void castpad_x_kernel(const float* __restrict__ x, unsigned short* __restrict__ xb) {
  int u = blockIdx.x * 256 + threadIdx.x;
  const int total = B_SZ * 200;
  const int stride = gridDim.x * 256;
  for (; u < total; u += stride) {
    const int row = u / 200, c4 = u - row * 200;
    ushort4 o = make_ushort4(0, 0, 0, 0);
    if (c4 < 196) {
      float4 v = *reinterpret_cast<const float4*>(x + (size_t)row * DIN + c4 * 4);
      o.x = f2bf(v.x); o.y = f2bf(v.y); o.z = f2bf(v.z); o.w = f2bf(v.w);
    }
    *reinterpret_cast<ushort4*>(xb + (size_t)row * DIN_P + c4 * 4) = o;
  }
}

// ---------------------------------------------------------------------------
// W [K][N] fp32 -> Wt [Npad][Kpad] bf16, zero-padded.
// ---------------------------------------------------------------------------
__global__ __launch_bounds__(256)
void wtrans_kernel(const float* __restrict__ W, unsigned short* __restrict__ Wt,
                   int K, int N, int Kpad) {
  const int k = blockIdx.x * 256 + threadIdx.x;
  const int n = blockIdx.y;
  if (k >= Kpad) return;
  const float v = (k < K && n < N) ? W[(size_t)k * N + n] : 0.f;
  Wt[(size_t)n * Kpad + k] = f2bf(v);
}

// ---------------------------------------------------------------------------
// MFMA GEMM: C = act(A @ Bt^T + bias).  A bf16 [M][Kpad] (rows optionally
// gathered via gidx), Bt bf16 [Npad][Kpad] (pre-transposed weight), BM=BN=128,
// BK=32, 256 threads = 4 waves in 2x2, acc 4x4 of 16x16x32 fragments.
// Double-buffered LDS staged with global_load_lds width 16 (linear layout:
// 64B row stride already spreads 64 lanes uniformly over 32 banks).
// ACT: 0=none 1=relu 2=sigmoid.  OUTF32: fp32 out with col<N guard (else bf16
// out [M][NpadOut], cols N..NpadOut-1 zeroed).  BCE: fused BCE partial sums.
// ---------------------------------------------------------------------------
template <int ACT, bool GATHER, bool BCE, bool OUTF32>
__global__ __launch_bounds__(256, 2)
void mgemm_kernel(const unsigned short* __restrict__ A,
                  const unsigned short* __restrict__ Bt,
                  const float* __restrict__ bias, void* __restrict__ C,
                  int N, int Kpad, int NpadOut,
                  const int* __restrict__ gidx,
                  const float* __restrict__ xg, float* __restrict__ loss_accum) {
  __shared__ __align__(16) unsigned short As[2][128 * 32];
  __shared__ __align__(16) unsigned short Bs[2][128 * 32];
  __shared__ int   sidx[128];
  __shared__ float rsum[256];

  const int tid  = threadIdx.x;
  const int w    = tid >> 6, lane = tid & 63;
  const int wr   = w >> 1, wc = w & 1;
  const int rowBase = blockIdx.y * 128, colBase = blockIdx.x * 128;

  if (GATHER) {
    if (tid < 128) sidx[tid] = gidx[rowBase + tid];
    __syncthreads();
  }

  const int srow  = lane >> 2;   // 0..15 within a 16-row group
  const int sunit = lane & 3;    // 16B unit within a 64B row

  auto stageA = [&](int kt, int bb) {
#pragma unroll
    for (int c = 0; c < 2; ++c) {
      const int rowq = (c * 4 + w) * 16 + srow;
      const long arow = GATHER ? (long)sidx[rowq] : (long)(rowBase + rowq);
      const unsigned short* g = A + (size_t)arow * Kpad + kt * 32 + sunit * 8;
      __builtin_amdgcn_global_load_lds(
          (const __attribute__((address_space(1))) unsigned int*)g,
          (__attribute__((address_space(3))) unsigned int*)
              &As[bb][(((c * 4 + w) * 64) + lane) * 8],
          16, 0, 0);
    }
  };
  auto stageB = [&](int kt, int bb) {
#pragma unroll
    for (int c = 0; c < 2; ++c) {
      const int rowq = (c * 4 + w) * 16 + srow;
      const unsigned short* g =
          Bt + (size_t)(colBase + rowq) * Kpad + kt * 32 + sunit * 8;
      __builtin_amdgcn_global_load_lds(
          (const __attribute__((address_space(1))) unsigned int*)g,
          (__attribute__((address_space(3))) unsigned int*)
              &Bs[bb][(((c * 4 + w) * 64) + lane) * 8],
          16, 0, 0);
    }
  };

  f32x4 acc[4][4] = {};
  stageA(0, 0); stageB(0, 0);
  const int nk = Kpad >> 5;
  const int lr = lane >> 4, lc = lane & 15;

  for (int kt = 0; kt < nk; ++kt) {
    const int bb = kt & 1;
    __syncthreads();  // compiler drains vmcnt before s_barrier
    if (kt + 1 < nk) { stageA(kt + 1, bb ^ 1); stageB(kt + 1, bb ^ 1); }
    bf16x8 a[4], b[4];
#pragma unroll
    for (int f = 0; f < 4; ++f) {
      const int ra = wr * 64 + f * 16 + lc;
      a[f] = *reinterpret_cast<const bf16x8*>(&As[bb][ra * 32 + lr * 8]);
      const int rb = wc * 64 + f * 16 + lc;
      b[f] = *reinterpret_cast<const bf16x8*>(&Bs[bb][rb * 32 + lr * 8]);
    }
#pragma unroll
    for (int i = 0; i < 4; ++i)
#pragma unroll
      for (int j = 0; j < 4; ++j)
        acc[i][j] =
            __builtin_amdgcn_mfma_f32_16x16x32_bf16(a[i], b[j], acc[i][j], 0, 0, 0);
  }

  // epilogue: C/D layout col=lane&15, row=(lane>>4)*4+reg
  float bce = 0.f;
#pragma unroll
  for (int j = 0; j < 4; ++j) {
    const int gcol = colBase + wc * 64 + j * 16 + lc;
    const float bj = (gcol < N) ? bias[gcol] : 0.f;
#pragma unroll
    for (int i = 0; i < 4; ++i) {
      const int growb = rowBase + wr * 64 + i * 16 + lr * 4;
#pragma unroll
      for (int r = 0; r < 4; ++r) {
        float v = acc[i][j][r] + bj;
        if (ACT == 1) v = fmaxf(v, 0.f);
        if (ACT == 2) v = 1.f / (1.f + expf(-v));
        const int grow = growb + r;
        if (OUTF32) {
          if (gcol < N) {
            ((float*)C)[(size_t)grow * N + gcol] = v;
            if (BCE) {
              const float p  = fminf(fmaxf(v, 1e-7f), 1.f - 1e-7f);
              const float xv = xg[(size_t)grow * N + gcol];
              bce += xv * logf(p) + (1.f - xv) * log1pf(-p);
            }
          }
        } else {
          if (gcol < NpadOut)
            ((unsigned short*)C)[(size_t)grow * NpadOut + gcol] =
                (gcol < N) ? f2bf(v) : (unsigned short)0;
        }
      }
    }
  }

  if (BCE) {
    rsum[tid] = bce;
    __syncthreads();
#pragma unroll
    for (int s = 128; s > 0; s >>= 1) {
      if (tid < s) rsum[tid] += rsum[tid + s];
      __syncthreads();
    }
    if (tid == 0) atomicAdd(loss_accum, rsum[0]);
  }
}

// ---------------------------------------------------------------------------
// MFMA VQ argmin (unchanged from round 2; verified).
// ---------------------------------------------------------------------------
__global__ __launch_bounds__(512, 2)
void vq_mfma_kernel(const unsigned short* __restrict__ zeb,
                    const unsigned short* __restrict__ embb,
                    const float* __restrict__ emb_sq,
                    float* __restrict__ cand_val, int* __restrict__ cand_idx) {
  __shared__ unsigned short etile[2][32 * 512];

  const int tid  = threadIdx.x;
  const int w    = tid >> 6;
  const int lane = tid & 63;
  const int cq   = lane >> 4;
  const int cr   = lane & 15;

  const int bid      = blockIdx.x;
  const int chunk    = (bid >> 1) & 3;
  const int rowblock = ((bid >> 3) << 1) | (bid & 1);
  const int rowBase  = rowblock * 256;
  const int codeBase = chunk * 2048;

  bf16x8 a[2][16];
  {
    const unsigned short* z0 =
        zeb + (size_t)(rowBase + w * 32 + cr) * D_SZ + cq * 8;
#pragma unroll
    for (int ks = 0; ks < 16; ++ks) {
      a[0][ks] = *reinterpret_cast<const bf16x8*>(z0 + ks * 32);
      a[1][ks] = *reinterpret_cast<const bf16x8*>(z0 + 16 * D_SZ + ks * 32);
    }
  }

  float minv[2][4];
  int   mini[2][4];
#pragma unroll
  for (int mf = 0; mf < 2; ++mf)
#pragma unroll
    for (int r4 = 0; r4 < 4; ++r4) { minv[mf][r4] = FLT_MAX; mini[mf][r4] = 0; }

  auto stage = [&](int tt, int bb) {
#pragma unroll
    for (int r = 0; r < 4; ++r) {
      const int row = r * 8 + w;
      const unsigned short* g =
          embb + (size_t)(codeBase + tt * 32 + row) * D_SZ + ((lane ^ w) << 3);
      __builtin_amdgcn_global_load_lds(
          (const __attribute__((address_space(1))) unsigned int*)g,
          (__attribute__((address_space(3))) unsigned int*)&etile[bb][row * D_SZ],
          16, 0, 0);
    }
  };

  stage(0, 0);
  __syncthreads();

  const char* lds0 = (const char*)etile[0];
  const char* lds1 = (const char*)etile[1];
  const int sw  = (cr & 7) << 4;
  const int rbA = cr * 1024;
  const int rbB = (16 + cr) * 1024;

#pragma unroll 2
  for (int t = 0; t < 64; ++t) {
    const int bb = t & 1;
    if (t + 1 < 64) stage(t + 1, bb ^ 1);
    const char* buf = bb ? lds1 : lds0;

    f32x4 acc[2][2] = {};
#pragma unroll
    for (int ks = 0; ks < 16; ++ks) {
      const int off = (ks * 64 + cq * 16) ^ sw;
      bf16x8 b0 = *reinterpret_cast<const bf16x8*>(buf + rbA + off);
      bf16x8 b1 = *reinterpret_cast<const bf16x8*>(buf + rbB + off);
      acc[0][0] = __builtin_amdgcn_mfma_f32_16x16x32_bf16(a[0][ks], b0, acc[0][0], 0, 0, 0);
      acc[1][0] = __builtin_amdgcn_mfma_f32_16x16x32_bf16(a[1][ks], b0, acc[1][0], 0, 0, 0);
      acc[0][1] = __builtin_amdgcn_mfma_f32_16x16x32_bf16(a[0][ks], b1, acc[0][1], 0, 0, 0);
      acc[1][1] = __builtin_amdgcn_mfma_f32_16x16x32_bf16(a[1][ks], b1, acc[1][1], 0, 0, 0);
    }

    const int tb = codeBase + t * 32;
#pragma unroll
    for (int nf = 0; nf < 2; ++nf) {
      const int c = tb + nf * 16 + cr;
      const float sq = emb_sq[c];
#pragma unroll
      for (int mf = 0; mf < 2; ++mf)
#pragma unroll
        for (int r4 = 0; r4 < 4; ++r4) {
          const float s = sq - 2.f * acc[mf][nf][r4];
          if (s < minv[mf][r4]) { minv[mf][r4] = s; mini[mf][r4] = c; }
        }
    }
    __syncthreads();
  }

#pragma unroll
  for (int mf = 0; mf < 2; ++mf)
#pragma unroll
    for (int r4 = 0; r4 < 4; ++r4) {
      float v = minv[mf][r4];
      int   i = mini[mf][r4];
#pragma unroll
      for (int m = 1; m < 16; m <<= 1) {
        float ov = __shfl_xor(v, m, 64);
        int   oi = __shfl_xor(i, m, 64);
        if (ov < v || (ov == v && oi < i)) { v = ov; i = oi; }
      }
      if (cr == 0) {
        const int row = rowBase + w * 32 + mf * 16 + cq * 4 + r4;
        cand_val[(size_t)chunk * B_SZ + row] = v;
        cand_idx[(size_t)chunk * B_SZ + row] = i;
      }
    }
}

// ---------------------------------------------------------------------------
__global__ __launch_bounds__(256)
void vq_finalize_kernel(const float* __restrict__ cv, const int* __restrict__ ci,
                        int* __restrict__ idx) {
  const int r = blockIdx.x * 256 + threadIdx.x;
  float bv = cv[r];
  int   bi = ci[r];
#pragma unroll
  for (int c = 1; c < 4; ++c) {
    const float v = cv[(size_t)c * B_SZ + r];
    const int  i2 = ci[(size_t)c * B_SZ + r];
    if (v < bv || (v == bv && i2 < bi)) { bv = v; bi = i2; }
  }
  idx[r] = bi;
}

// ---------------------------------------------------------------------------
// sum((z_e - emb[idx])^2) -> accum[1], z_e read back from bf16 zeb
// ---------------------------------------------------------------------------
__global__ __launch_bounds__(256)
void vqloss_kernel(const unsigned short* __restrict__ zeb,
                   const float* __restrict__ emb,
                   const int* __restrict__ idx, float* __restrict__ accum) {
  __shared__ float rsum[256];
  const int tid = threadIdx.x;
  const size_t stride = (size_t)gridDim.x * 256;
  const size_t total = (size_t)B_SZ * (D_SZ / 8);
  float s = 0.f;
  for (size_t e = (size_t)blockIdx.x * 256 + tid; e < total; e += stride) {
    const size_t b = e >> 6;
    const int   d8 = (int)(e & 63);
    bf16x8 z = *reinterpret_cast<const bf16x8*>(zeb + b * D_SZ + d8 * 8);
    const float* q = emb + (size_t)idx[b] * D_SZ + d8 * 8;
    const float4 q0 = *reinterpret_cast<const float4*>(q);
    const float4 q1 = *reinterpret_cast<const float4*>(q + 4);
    const float qa[8] = {q0.x, q0.y, q0.z, q0.w, q1.x, q1.y, q1.z, q1.w};
#pragma unroll
    for (int j = 0; j < 8; ++j) {
      const float d = bf2f((unsigned short)z[j]) - qa[j];
      s += d * d;
    }
  }
  rsum[tid] = s;
  __syncthreads();
#pragma unroll
  for (int st = 128; st > 0; st >>= 1) {
    if (tid < st) rsum[tid] += rsum[tid + st];
    __syncthreads();
  }
  if (tid == 0) atomicAdd(accum + 1, rsum[0]);
}

// ---------------------------------------------------------------------------
__global__ void finalize_kernel(const float* __restrict__ accum,
                                float* __restrict__ out) {
  const float rl = -accum[0] / ((float)B_SZ * (float)DIN);
  const float el = accum[1] / (float)B_SZ;
  out[(size_t)B_SZ * DIN + 0] = rl;
  out[(size_t)B_SZ * DIN + 1] = el;
  out[(size_t)B_SZ * DIN + 2] = el;
}

// ---------------------------------------------------------------------------
extern "C" void kernel_launch(void* const* d_in, const int* in_sizes, int n_in,
                              void* d_out, int out_size, void* d_ws,
                              size_t ws_size, hipStream_t stream) {
  const float* x   = (const float*)d_in[0];
  const float* W1  = (const float*)d_in[1];
  const float* b1  = (const float*)d_in[2];
  const float* W2  = (const float*)d_in[3];
  const float* b2  = (const float*)d_in[4];
  const float* W3  = (const float*)d_in[5];
  const float* b3  = (const float*)d_in[6];
  const float* W4  = (const float*)d_in[7];
  const float* b4  = (const float*)d_in[8];
  const float* emb = (const float*)d_in[9];
  float* out = (float*)d_out;

  // ---- workspace layout (bytes, 256-aligned bumps) ----
  char* wsb = (char*)d_ws;
  auto alloc = [&](size_t bytes) {
    char* p = wsb;
    wsb += (bytes + 255) & ~(size_t)255;
    return p;
  };
  const size_t xb_bytes   = (size_t)B_SZ * DIN_P * 2;          // 26.2 MB
  const size_t zeb_bytes  = (size_t)B_SZ * D_SZ * 2;           // 16.8 MB
  const size_t embb_bytes = (size_t)K_SZ * D_SZ * 2;           //  8.4 MB
  char* regionA = alloc(xb_bytes);  // xb, later zeb+embb (xb dead after gemm1)
  unsigned short* xb   = (unsigned short*)regionA;
  unsigned short* zeb  = (unsigned short*)regionA;
  unsigned short* embb = (unsigned short*)(regionA + zeb_bytes);
  (void)embb_bytes;
  char* regionB = alloc((size_t)B_SZ * H_P * 2);  // h1b, later h3b
  unsigned short* h1b = (unsigned short*)regionB;
  unsigned short* h3b = (unsigned short*)regionB;
  unsigned short* W1t = (unsigned short*)alloc((size_t)512 * DIN_P * 2);
  unsigned short* W2t = (unsigned short*)alloc((size_t)512 * H_P * 2);
  unsigned short* W3t = (unsigned short*)alloc((size_t)512 * D_SZ * 2);
  unsigned short* W4t = (unsigned short*)alloc((size_t)896 * H_P * 2);
  float* esq   = (float*)alloc((size_t)K_SZ * 4);
  float* accum = (float*)alloc(64);
  int*   idx   = (int*)alloc((size_t)B_SZ * 4);
  float* cand_val = (float*)alloc((size_t)4 * B_SZ * 4);
  int*   cand_idx = (int*)alloc((size_t)4 * B_SZ * 4);

  // 1) codebook norms + zero accumulators
  embsq_kernel<<<K_SZ / 4, 256, 0, stream>>>(emb, esq, accum);
  // 2) prepare bf16 operands
  castpad_x_kernel<<<2048, 256, 0, stream>>>(x, xb);
  wtrans_kernel<<<dim3(4, 512), 256, 0, stream>>>(W1, W1t, DIN, H_SZ, DIN_P);
  wtrans_kernel<<<dim3(2, 512), 256, 0, stream>>>(W2, W2t, H_SZ, D_SZ, H_P);
  wtrans_kernel<<<dim3(2, 512), 256, 0, stream>>>(W3, W3t, D_SZ, H_SZ, D_SZ);
  wtrans_kernel<<<dim3(2, 896), 256, 0, stream>>>(W4, W4t, H_SZ, DIN, H_P);
  // 3) h1 = relu(x @ W1 + b1)           (bf16 out, padded cols zeroed)
  mgemm_kernel<1, false, false, false><<<dim3(4, B_SZ / 128), 256, 0, stream>>>(
      xb, W1t, b1, h1b, H_SZ, DIN_P, H_P, nullptr, nullptr, nullptr);
  // 4) emb -> bf16 (region overlapped with now-dead xb tail)
  cast_bf16_kernel<<<1024, 256, 0, stream>>>(emb, embb, (K_SZ * D_SZ) / 4);
  // 5) z_e = h1 @ W2 + b2               (bf16 out = zeb)
  mgemm_kernel<0, false, false, false><<<dim3(4, B_SZ / 128), 256, 0, stream>>>(
      h1b, W2t, b2, zeb, D_SZ, H_P, D_SZ, nullptr, nullptr, nullptr);
  // 6) VQ argmin
  vq_mfma_kernel<<<256, 512, 0, stream>>>(zeb, embb, esq, cand_val, cand_idx);
  vq_finalize_kernel<<<B_SZ / 256, 256, 0, stream>>>(cand_val, cand_idx, idx);
  // 7) embed/commit loss
  vqloss_kernel<<<1024, 256, 0, stream>>>(zeb, emb, idx, accum);
  // 8) h3 = relu(emb[idx] @ W3 + b3)    (gathered bf16 A)
  mgemm_kernel<1, true, false, false><<<dim3(4, B_SZ / 128), 256, 0, stream>>>(
      embb, W3t, b3, h3b, H_SZ, D_SZ, H_P, idx, nullptr, nullptr);
  // 9) x_reconst = sigmoid(h3 @ W4 + b4), fused BCE
  mgemm_kernel<2, false, true, true><<<dim3(7, B_SZ / 128), 256, 0, stream>>>(
      h3b, W4t, b4, out, DIN, H_P, DIN, nullptr, x, accum);
  // 10) scalars
  finalize_kernel<<<1, 1, 0, stream>>>(accum, out);
}